// Round 16
// baseline (317.704 us; speedup 1.0000x reference)
//
#include <hip/hip_runtime.h>
#include <hip/hip_bf16.h>
#include <math.h>

// SelfRetentionV1: B=2,H=16,L=2048,DK=128,DV=128
// out[b,l,h,d] = RMSNorm_d( (QK^T * gamma^(i-j) / max(1,|rowsum|)) @ V )
#define B_ 2
#define H_ 16
#define L_ 2048
#define DK_ 128
#define DV_ 128
#define QBLK 64
#define KVBLK 64

typedef __bf16 bf16x8 __attribute__((ext_vector_type(8)));
typedef float  f32x16 __attribute__((ext_vector_type(16)));

static __device__ __forceinline__ unsigned short f2bf(float f) {
    union { float f; unsigned int u; } x; x.f = f;
    unsigned int r = x.u + 0x7fffu + ((x.u >> 16) & 1u);  // RNE
    return (unsigned short)(r >> 16);
}

// async global->LDS, 16B per lane; LDS dest = wave-uniform base + lane*16
static __device__ __forceinline__ void gload_lds16(const void* g, void* l) {
    __builtin_amdgcn_global_load_lds(
        (const __attribute__((address_space(1))) unsigned int*)g,
        (__attribute__((address_space(3))) unsigned int*)l,
        16, 0, 0);
}

// K tile rows are 256B: swizzle bits 4-6 by row&7 (involution, row bits >=8)
#define KSWZ(d) ((d) ^ ((((d) >> 8) & 7) << 4))
// V tile rows are 128B: row bits >=7
#define VSWZ(d) ((d) ^ ((((d) >> 7) & 7) << 4))

// ---- fused pre-pass (unchanged from r15): K fp32->bf16 scaled by
// gamma_h^-(j&63); V -> VT[bh][dv][perm(l)]; fp32 row-0 fixup ----
__global__ void prep_kernel(const float* __restrict__ kin,
                            unsigned short* __restrict__ kb,
                            const float* __restrict__ v,
                            unsigned short* __restrict__ vt,
                            const float* __restrict__ q,
                            float* __restrict__ out) {
    __shared__ unsigned short lds[64][130];   // +2 pad (transpose half only)
    int bid = blockIdx.x;
    if (bid >= 2048) {                 // row-0 fixup, 32 blocks, wave 0 only
        if (threadIdx.x < 64) {
            int bh = bid - 2048;
            int lane = threadIdx.x;
            const float* qp = q   + (size_t)bh * L_ * DK_;
            const float* kp = kin + (size_t)bh * L_ * DK_;
            const float* vp = v   + (size_t)bh * L_ * DV_;
            float part = qp[lane] * kp[lane] + qp[lane + 64] * kp[lane + 64];
            #pragma unroll
            for (int mm = 1; mm < 64; mm <<= 1) part += __shfl_xor(part, mm);
            float cf = part / fmaxf(1.0f, fabsf(part));
            float o0 = cf * vp[lane], o1 = cf * vp[lane + 64];
            float ss = o0 * o0 + o1 * o1;
            #pragma unroll
            for (int mm = 1; mm < 64; mm <<= 1) ss += __shfl_xor(ss, mm);
            float sc = rsqrtf(ss * (1.0f / 128.0f) + 1e-6f);
            int b = bh >> 4, h = bh & 15;
            float* op = out + ((size_t)b * L_ * H_ + h) * DV_;   // i = 0
            op[lane] = o0 * sc;
            op[lane + 64] = o1 * sc;
        }
        return;
    }
    if (bid < 1024) {
        // K scale-convert: exact-fit grid-stride, 8 iters/thread; j invariant,
        // h cycles period-4 -> 4 precomputed scales (pure-BW pass).
        int i0 = bid * 256 + threadIdx.x;
        int j  = (i0 >> 5) & (L_ - 1);
        float sj = -(float)(j & 63);
        int h0 = (i0 >> 16) & (H_ - 1);
        float s4[4];
        #pragma unroll
        for (int c = 0; c < 4; ++c) {
            int hh = (h0 + 4 * c) & (H_ - 1);
            float l2g = log1pf(-exp2f((float)(-5 - hh))) * 1.44269504088896f;
            s4[c] = exp2f(l2g * sj);
        }
        #pragma unroll
        for (int n = 0; n < 8; ++n) {
            int idx = i0 + n * 262144;
            float s = s4[n & 3];
            float4 f = ((const float4*)kin)[idx];
            uint2 o;
            o.x = (unsigned)f2bf(f.x * s) | ((unsigned)f2bf(f.y * s) << 16);
            o.y = (unsigned)f2bf(f.z * s) | ((unsigned)f2bf(f.w * s) << 16);
            ((uint2*)kb)[idx] = o;
        }
        return;
    }
    int blk = bid - 1024;
    int ltile = blk & (L_/64 - 1);
    int bh = blk / (L_/64);
    const float* vp = v + ((size_t)bh * L_ + (size_t)ltile * 64) * DV_;
    unsigned short* vo = vt + (size_t)bh * DV_ * L_ + ltile * 64;
    int t = threadIdx.x;
    int r0 = t >> 5, c0 = (t & 31) * 4;
    #pragma unroll
    for (int it = 0; it < 8; ++it) {
        int row = r0 + 8 * it;
        float4 f = *(const float4*)(vp + row * DV_ + c0);
        lds[row][c0 + 0] = f2bf(f.x);
        lds[row][c0 + 1] = f2bf(f.y);
        lds[row][c0 + 2] = f2bf(f.z);
        lds[row][c0 + 3] = f2bf(f.w);
    }
    __syncthreads();
    int dvb = t >> 3, seg = t & 7;
    #pragma unroll
    for (int ot = 0; ot < 4; ++ot) {
        int dv = dvb + 32 * ot;
        unsigned short a[8];
        #pragma unroll
        for (int tt = 0; tt < 8; ++tt) {
            int pp = seg * 8 + tt;
            int js = (pp & ~12) | ((pp & 4) << 1) | ((pp & 8) >> 1);  // swap b2,b3
            a[tt] = lds[js][dv];
        }
        uint4 st;
        st.x = (unsigned)a[0] | ((unsigned)a[1] << 16);
        st.y = (unsigned)a[2] | ((unsigned)a[3] << 16);
        st.z = (unsigned)a[4] | ((unsigned)a[5] << 16);
        st.w = (unsigned)a[6] | ((unsigned)a[7] << 16);
        *(uint4*)(vo + (size_t)dv * L_ + seg * 8) = st;
    }
}

#define TREE16(v) ((((v[0]+v[1])+(v[2]+v[3]))+((v[4]+v[5])+(v[6]+v[7]))) \
                 + (((v[8]+v[9])+(v[10]+v[11]))+((v[12]+v[13])+(v[14]+v[15]))))

// One pipeline round at static buffer offset CUR, staging jt+1 into NXT.
// Protocol = proven r10/r14: vmcnt(8) counted wait, 2 s_barrier.
// SHARED-KV: every round computes segment B (q-tile jB); rounds jt<=jA
// also compute segment A, REUSING the same K/V LDS fragments (one read,
// two MFMAs). B's diagonal is the last round (jB > jA always).
#define ROUND(CUR, NXT)                                                       \
{                                                                             \
    if (jt < jB) {                                                            \
        const char* ksrc = (const char*)(kbp + (size_t)(jt + 1) * KVBLK * DK_);\
        const char* vsrc = (const char*)(vtp + (jt + 1) * KVBLK);             \
        _Pragma("unroll")                                                     \
        for (int is = 0; is < 4; ++is) {                                      \
            gload_lds16(ksrc + koff[is], kLDSw + (NXT) + dwv[is]);            \
            gload_lds16(vsrc + voff[is], vLDSw + (NXT) + dwv[is]);            \
        }                                                                     \
        asm volatile("s_waitcnt vmcnt(8)" ::: "memory");                      \
    } else {                                                                  \
        asm volatile("s_waitcnt vmcnt(0)" ::: "memory");                      \
    }                                                                         \
    asm volatile("s_barrier" ::: "memory");                                   \
    if (jt <= jA) {                                                           \
        f32x16 sA, sB;                                                        \
        _Pragma("unroll")                                                     \
        for (int e = 0; e < 16; ++e) { sA[e] = 0.0f; sB[e] = 0.0f; }          \
        __builtin_amdgcn_s_setprio(1);                                        \
        _Pragma("unroll")                                                     \
        for (int ks = 0; ks < 8; ++ks) {                                      \
            bf16x8 kf = *(const bf16x8*)(kBase + (CUR) + kxo[ks]);            \
            sA = __builtin_amdgcn_mfma_f32_32x32x16_bf16(kf, qfA[ks], sA, 0, 0, 0); \
            sB = __builtin_amdgcn_mfma_f32_32x32x16_bf16(kf, qfB[ks], sB, 0, 0, 0); \
        }                                                                     \
        __builtin_amdgcn_s_setprio(0);                                        \
        float valA[16], valB[16];                                             \
        if (jt == jA) {                                                       \
            _Pragma("unroll")                                                 \
            for (int r = 0; r < 16; ++r) {                                    \
                float vv = sA[r] * arowA;                                     \
                valA[r] = ((mbits >> r) & 1) ? vv : 0.0f;                     \
            }                                                                 \
        } else {                                                              \
            _Pragma("unroll")                                                 \
            for (int r = 0; r < 16; ++r) valA[r] = sA[r] * arowA;             \
        }                                                                     \
        _Pragma("unroll")                                                     \
        for (int r = 0; r < 16; ++r) valB[r] = sB[r] * arowB;                 \
        arowA *= gm64i;                                                       \
        arowB *= gm64i;                                                       \
        rowsumA += TREE16(valA);                                              \
        rowsumB += TREE16(valB);                                              \
        union { bf16x8 v; __bf16 e[8]; } PA0, PA1, PB0, PB1;                  \
        _Pragma("unroll")                                                     \
        for (int e = 0; e < 8; ++e) {                                         \
            PA0.e[e] = (__bf16)valA[e]; PA1.e[e] = (__bf16)valA[8 + e];       \
            PB0.e[e] = (__bf16)valB[e]; PB1.e[e] = (__bf16)valB[8 + e];       \
        }                                                                     \
        __builtin_amdgcn_s_setprio(1);                                        \
        _Pragma("unroll")                                                     \
        for (int nt = 0; nt < 4; ++nt) {                                      \
            bf16x8 vb0 = *(const bf16x8*)(vBase[nt] + (CUR) + vxo0);          \
            oA[nt] = __builtin_amdgcn_mfma_f32_32x32x16_bf16(PA0.v, vb0, oA[nt], 0, 0, 0); \
            oB[nt] = __builtin_amdgcn_mfma_f32_32x32x16_bf16(PB0.v, vb0, oB[nt], 0, 0, 0); \
            bf16x8 vb1 = *(const bf16x8*)(vBase[nt] + (CUR) + vxo1);          \
            oA[nt] = __builtin_amdgcn_mfma_f32_32x32x16_bf16(PA1.v, vb1, oA[nt], 0, 0, 0); \
            oB[nt] = __builtin_amdgcn_mfma_f32_32x32x16_bf16(PB1.v, vb1, oB[nt], 0, 0, 0); \
        }                                                                     \
        __builtin_amdgcn_s_setprio(0);                                        \
    } else {                                                                  \
        f32x16 sB;                                                            \
        _Pragma("unroll")                                                     \
        for (int e = 0; e < 16; ++e) sB[e] = 0.0f;                            \
        __builtin_amdgcn_s_setprio(1);                                        \
        _Pragma("unroll")                                                     \
        for (int ks = 0; ks < 8; ++ks) {                                      \
            bf16x8 kf = *(const bf16x8*)(kBase + (CUR) + kxo[ks]);            \
            sB = __builtin_amdgcn_mfma_f32_32x32x16_bf16(kf, qfB[ks], sB, 0, 0, 0); \
        }                                                                     \
        __builtin_amdgcn_s_setprio(0);                                        \
        float valB[16];                                                       \
        if (jt == jB) {                                                       \
            _Pragma("unroll")                                                 \
            for (int r = 0; r < 16; ++r) {                                    \
                float vv = sB[r] * arowB;                                     \
                valB[r] = ((mbits >> r) & 1) ? vv : 0.0f;                     \
            }                                                                 \
        } else {                                                              \
            _Pragma("unroll")                                                 \
            for (int r = 0; r < 16; ++r) valB[r] = sB[r] * arowB;             \
        }                                                                     \
        arowB *= gm64i;                                                       \
        rowsumB += TREE16(valB);                                              \
        union { bf16x8 v; __bf16 e[8]; } PB0, PB1;                            \
        _Pragma("unroll")                                                     \
        for (int e = 0; e < 8; ++e) {                                         \
            PB0.e[e] = (__bf16)valB[e]; PB1.e[e] = (__bf16)valB[8 + e];       \
        }                                                                     \
        __builtin_amdgcn_s_setprio(1);                                        \
        _Pragma("unroll")                                                     \
        for (int nt = 0; nt < 4; ++nt) {                                      \
            bf16x8 vb0 = *(const bf16x8*)(vBase[nt] + (CUR) + vxo0);          \
            oB[nt] = __builtin_amdgcn_mfma_f32_32x32x16_bf16(PB0.v, vb0, oB[nt], 0, 0, 0); \
            bf16x8 vb1 = *(const bf16x8*)(vBase[nt] + (CUR) + vxo1);          \
            oB[nt] = __builtin_amdgcn_mfma_f32_32x32x16_bf16(PB1.v, vb1, oB[nt], 0, 0, 0); \
        }                                                                     \
        __builtin_amdgcn_s_setprio(0);                                        \
    }                                                                         \
    asm volatile("s_barrier" ::: "memory");                                   \
}

// ---- main kernel: r10 geometry (4 waves rh/kh, QBLK=KVBLK=64, dbuf,
// 2 blocks/CU) with SHARED-KV dual-segment blocks: block (bh, sp) runs
// ONE kv sweep 0..31-sp serving q-tiles A=sp and B=31-sp. Rounds/block
// 34 -> 32-sp; staged bytes -26%; K/V frags read once feed both segments.
// Balance: bid c and c+256 co-resident pair sp with 15-sp -> 49
// round-slots per CU, constant. XCD pinning preserved (256 % 8 == 0).
__launch_bounds__(256, 2)
__global__ void retention_kernel(const float* __restrict__ q,
                                 const unsigned short* __restrict__ kb,
                                 const unsigned short* __restrict__ vt_,
                                 float* __restrict__ out) {
    __shared__ __align__(16) unsigned short kbuf[2][64 * 128];   // 32 KB
    __shared__ __align__(16) unsigned short vbuf[2][128 * 64];   // 32 KB
    __shared__ float rsxA[64], rsxB[64];

    int bid = blockIdx.x;            // 0..511
    int sec = bid >> 8;              // residency half (pairs sp with 15-sp)
    int lo  = bid & 255;
    int x   = lo & 7;                // XCD id
    int t_  = lo >> 3;               // 0..31
    int spp = t_ & 15;
    int hi  = (t_ >> 4) + 2 * sec;   // 0..3
    int sp  = sec ? (15 - spp) : spp;
    int bh  = hi * 8 + x;
    int b = bh >> 4, h = bh & 15;
    int jA = sp, jB = 31 - sp;

    int tid = threadIdx.x;
    int lane = tid & 63;
    int w = tid >> 6;                   // 0..3
    int rh = w >> 1;                    // q-row half (within each 64-row tile)
    int kh = w & 1;                     // kv half
    int il = lane & 31;
    int hl = lane >> 5;

    const unsigned short* kbp = kb  + (size_t)bh * L_ * DK_;
    const unsigned short* vtp = vt_ + (size_t)bh * DV_ * L_;

    // hoisted per-lane stage offsets (loop-invariant)
    int dwv[4], koff[4], voff[4];
    #pragma unroll
    for (int is = 0; is < 4; ++is) {
        int dw = is * 4096 + w * 1024;
        int d  = dw + lane * 16;
        dwv[is]  = dw;
        koff[is] = KSWZ(d);
        int sv   = VSWZ(d);
        voff[is] = (sv >> 7) * (L_ * 2) + (sv & 127);
    }
    char* kLDSw = (char*)&kbuf[0][0];
    char* vLDSw = (char*)&vbuf[0][0];

    float ex = exp2f((float)(-5 - h));
    float log2g = log1pf(-ex) * 1.44269504088896f;
    float gm64i = exp2f(log2g * (-64.0f));

    // diag mask (same geometry for both segments): keep iff j_loc <= i_loc
    int icmp = rh * 32 + il - kh * 32;
    unsigned mbits = 0;
    #pragma unroll
    for (int r = 0; r < 16; ++r)
        if (((r & 3) + 8 * (r >> 2) + 4 * hl) <= icmp) mbits |= 1u << r;

    int rswz = (il & 7) << 4;           // read-side XOR (rows == il mod 8)
    int hl16 = hl * 16;

    // LDS read bases/offsets
    const char* kBase = (const char*)&kbuf[0][0] + (kh * 32 + il) * 256;
    int kxo[8];
    #pragma unroll
    for (int ks = 0; ks < 8; ++ks) kxo[ks] = (ks * 32 + hl16) ^ rswz;
    const char* vBase[4];
    #pragma unroll
    for (int nt = 0; nt < 4; ++nt)
        vBase[nt] = (const char*)&vbuf[0][0] + (nt * 32 + il) * 128;
    int vxo0 = (kh * 64 + hl16) ^ rswz;
    int vxo1 = (kh * 64 + 32 + hl16) ^ rswz;

    int i0A = jA * QBLK + rh * 32;
    int i0B = jB * QBLK + rh * 32;

    // ---- Q fragments for BOTH segments (B-operand, col = il) ----
    bf16x8 qfA[8], qfB[8];
    {
        const float* qpa = q + ((size_t)bh * L_ + (i0A + il)) * DK_ + hl * 8;
        const float* qpb = q + ((size_t)bh * L_ + (i0B + il)) * DK_ + hl * 8;
        #pragma unroll
        for (int ks = 0; ks < 8; ++ks) {
            float4 f0 = *(const float4*)(qpa + ks * 16);
            float4 f1 = *(const float4*)(qpa + ks * 16 + 4);
            union { bf16x8 v; unsigned short u[8]; } A;
            A.u[0]=f2bf(f0.x); A.u[1]=f2bf(f0.y); A.u[2]=f2bf(f0.z); A.u[3]=f2bf(f0.w);
            A.u[4]=f2bf(f1.x); A.u[5]=f2bf(f1.y); A.u[6]=f2bf(f1.z); A.u[7]=f2bf(f1.w);
            qfA[ks] = A.v;
            float4 g0 = *(const float4*)(qpb + ks * 16);
            float4 g1 = *(const float4*)(qpb + ks * 16 + 4);
            union { bf16x8 v; unsigned short u[8]; } Bu;
            Bu.u[0]=f2bf(g0.x); Bu.u[1]=f2bf(g0.y); Bu.u[2]=f2bf(g0.z); Bu.u[3]=f2bf(g0.w);
            Bu.u[4]=f2bf(g1.x); Bu.u[5]=f2bf(g1.y); Bu.u[6]=f2bf(g1.z); Bu.u[7]=f2bf(g1.w);
            qfB[ks] = Bu.v;
        }
    }

    // ---- stage tile 0 into buffer offset 0 ----
    {
        const char* ksrc = (const char*)kbp;
        const char* vsrc = (const char*)vtp;
        #pragma unroll
        for (int is = 0; is < 4; ++is) {
            gload_lds16(ksrc + koff[is], kLDSw + dwv[is]);
            gload_lds16(vsrc + voff[is], vLDSw + dwv[is]);
        }
    }

    // row decay: gamma^(i - 64*jt); K' carries gamma^-(j&63)
    float arowA = exp2f(log2g * (float)(i0A + il));
    float arowB = exp2f(log2g * (float)(i0B + il));

    f32x16 oA[4], oB[4];
    #pragma unroll
    for (int nt = 0; nt < 4; ++nt)
        #pragma unroll
        for (int e = 0; e < 16; ++e) { oA[nt][e] = 0.0f; oB[nt][e] = 0.0f; }
    float rowsumA = 0.0f, rowsumB = 0.0f;

    int jt = 0;
    while (true) {                      // static buffer alternation
        ROUND(0, 16384);
        if (++jt > jB) break;
        ROUND(16384, 0);
        if (++jt > jB) break;
    }

    // ---- epilogue: combine hl halves, cross-kh via LDS, both segments ----
    float rswA = rowsumA + __shfl_xor(rowsumA, 32);
    float rswB = rowsumB + __shfl_xor(rowsumB, 32);

    __syncthreads();   // all tile reads done before buffer reuse
    float* ebA = (float*)&kbuf[0][0] + rh * 4096;   // 16KB per rh
    float* ebB = (float*)&vbuf[0][0] + rh * 4096;
    if (kh == 1) {
        #pragma unroll
        for (int nt = 0; nt < 4; ++nt)
            #pragma unroll
            for (int qq = 0; qq < 4; ++qq) {
                float4 va = { oA[nt][4*qq+0], oA[nt][4*qq+1],
                              oA[nt][4*qq+2], oA[nt][4*qq+3] };
                *(float4*)(ebA + (nt * 4 + qq) * 256 + lane * 4) = va;
                float4 vb = { oB[nt][4*qq+0], oB[nt][4*qq+1],
                              oB[nt][4*qq+2], oB[nt][4*qq+3] };
                *(float4*)(ebB + (nt * 4 + qq) * 256 + lane * 4) = vb;
            }
        if (lane < 32) {
            rsxA[rh * 32 + lane] = rswA;
            rsxB[rh * 32 + lane] = rswB;
        }
    }
    __syncthreads();
    if (kh == 0) {
        #pragma unroll
        for (int nt = 0; nt < 4; ++nt)
            #pragma unroll
            for (int qq = 0; qq < 4; ++qq) {
                float4 pa = *(const float4*)(ebA + (nt * 4 + qq) * 256 + lane * 4);
                oA[nt][4*qq+0] += pa.x; oA[nt][4*qq+1] += pa.y;
                oA[nt][4*qq+2] += pa.z; oA[nt][4*qq+3] += pa.w;
                float4 pb = *(const float4*)(ebB + (nt * 4 + qq) * 256 + lane * 4);
                oB[nt][4*qq+0] += pb.x; oB[nt][4*qq+1] += pb.y;
                oB[nt][4*qq+2] += pb.z; oB[nt][4*qq+3] += pb.w;
            }
        float dnlA = 1.0f / fmaxf(1.0f, fabsf(rswA + rsxA[rh * 32 + il]));
        float dnlB = 1.0f / fmaxf(1.0f, fabsf(rswB + rsxB[rh * 32 + il]));

        #pragma unroll
        for (int r = 0; r < 16; ++r) {
            int isrc = (r & 3) + 8 * (r >> 2) + 4 * hl;
            // segment A
            {
                float dn = __shfl(dnlA, isrc);
                float ov[4]; float ss = 0.0f;
                #pragma unroll
                for (int nt = 0; nt < 4; ++nt) { ov[nt] = oA[nt][r] * dn; ss += ov[nt]*ov[nt]; }
                ss += __shfl_xor(ss, 1);  ss += __shfl_xor(ss, 2);
                ss += __shfl_xor(ss, 4);  ss += __shfl_xor(ss, 8);
                ss += __shfl_xor(ss, 16);
                float sc = rsqrtf(ss * (1.0f / 128.0f) + 1e-6f);
                int i_abs = i0A + isrc;
                if (i_abs != 0) {               // row 0 handled in prep (fp32)
                    float* op = out + (((size_t)b * L_ + i_abs) * H_ + h) * DV_ + il;
                    #pragma unroll
                    for (int nt = 0; nt < 4; ++nt) op[nt * 32] = ov[nt] * sc;
                }
            }
            // segment B
            {
                float dn = __shfl(dnlB, isrc);
                float ov[4]; float ss = 0.0f;
                #pragma unroll
                for (int nt = 0; nt < 4; ++nt) { ov[nt] = oB[nt][r] * dn; ss += ov[nt]*ov[nt]; }
                ss += __shfl_xor(ss, 1);  ss += __shfl_xor(ss, 2);
                ss += __shfl_xor(ss, 4);  ss += __shfl_xor(ss, 8);
                ss += __shfl_xor(ss, 16);
                float sc = rsqrtf(ss * (1.0f / 128.0f) + 1e-6f);
                int i_abs = i0B + isrc;
                float* op = out + (((size_t)b * L_ + i_abs) * H_ + h) * DV_ + il;
                #pragma unroll
                for (int nt = 0; nt < 4; ++nt) op[nt * 32] = ov[nt] * sc;
            }
        }
    }
}

extern "C" void kernel_launch(void* const* d_in, const int* in_sizes, int n_in,
                              void* d_out, int out_size, void* d_ws, size_t ws_size,
                              hipStream_t stream) {
    const float* q = (const float*)d_in[0];
    const float* k = (const float*)d_in[1];
    const float* v = (const float*)d_in[2];
    // d_in[3] decay_mask (256MB) and d_in[4] intra_decay are recomputed on the fly
    float* out = (float*)d_out;

    unsigned short* kb = (unsigned short*)d_ws;                 // 16 MB
    unsigned short* vt = kb + (size_t)B_ * H_ * L_ * DK_;       // 16 MB

    prep_kernel<<<2080, 256, 0, stream>>>(k, kb, v, vt, q, out);
    retention_kernel<<<512, 256, 0, stream>>>(q, kb, vt, out);
}

// Round 17
// 79.754 us; speedup vs baseline: 3.9836x; 3.9836x over previous
//
#include <hip/hip_runtime.h>
#include <hip/hip_bf16.h>
#include <math.h>

// SelfRetentionV1: B=2,H=16,L=2048,DK=128,DV=128
// out[b,l,h,d] = RMSNorm_d( (QK^T * gamma^(i-j) / max(1,|rowsum|)) @ V )
#define B_ 2
#define H_ 16
#define L_ 2048
#define DK_ 128
#define DV_ 128
#define QBLK 64
#define KVBLK 64

typedef __bf16 bf16x8 __attribute__((ext_vector_type(8)));
typedef float  f32x16 __attribute__((ext_vector_type(16)));

static __device__ __forceinline__ unsigned short f2bf(float f) {
    union { float f; unsigned int u; } x; x.f = f;
    unsigned int r = x.u + 0x7fffu + ((x.u >> 16) & 1u);  // RNE
    return (unsigned short)(r >> 16);
}

// async global->LDS, 16B per lane; LDS dest = wave-uniform base + lane*16
static __device__ __forceinline__ void gload_lds16(const void* g, void* l) {
    __builtin_amdgcn_global_load_lds(
        (const __attribute__((address_space(1))) unsigned int*)g,
        (__attribute__((address_space(3))) unsigned int*)l,
        16, 0, 0);
}

// K tile rows are 256B: swizzle bits 4-6 by row&7 (involution, row bits >=8)
#define KSWZ(d) ((d) ^ ((((d) >> 8) & 7) << 4))
// V tile rows are 128B: row bits >=7
#define VSWZ(d) ((d) ^ ((((d) >> 7) & 7) << 4))

// ---- fused pre-pass: blocks 0..1023 convert K fp32->bf16 SCALED BY
// gamma_h^-(j&63) (folds the per-column decay out of the hot loop);
// 1024..2047 transpose V -> VT[bh][dv][perm(l)] (bit2<->3 perm);
// 2048..2079 fp32 row-0 fixup (retention skips its row-0 store) ----
__global__ void prep_kernel(const float* __restrict__ kin,
                            unsigned short* __restrict__ kb,
                            const float* __restrict__ v,
                            unsigned short* __restrict__ vt,
                            const float* __restrict__ q,
                            float* __restrict__ out) {
    __shared__ unsigned short lds[64][130];   // +2 pad (transpose half only)
    int bid = blockIdx.x;
    if (bid >= 2048) {                 // row-0 fixup, 32 blocks, wave 0 only
        if (threadIdx.x < 64) {
            int bh = bid - 2048;
            int lane = threadIdx.x;
            const float* qp = q   + (size_t)bh * L_ * DK_;
            const float* kp = kin + (size_t)bh * L_ * DK_;
            const float* vp = v   + (size_t)bh * L_ * DV_;
            float part = qp[lane] * kp[lane] + qp[lane + 64] * kp[lane + 64];
            #pragma unroll
            for (int mm = 1; mm < 64; mm <<= 1) part += __shfl_xor(part, mm);
            float cf = part / fmaxf(1.0f, fabsf(part));
            float o0 = cf * vp[lane], o1 = cf * vp[lane + 64];
            float ss = o0 * o0 + o1 * o1;
            #pragma unroll
            for (int mm = 1; mm < 64; mm <<= 1) ss += __shfl_xor(ss, mm);
            float sc = rsqrtf(ss * (1.0f / 128.0f) + 1e-6f);
            int b = bh >> 4, h = bh & 15;
            float* op = out + ((size_t)b * L_ * H_ + h) * DV_;   // i = 0
            op[lane] = o0 * sc;
            op[lane + 64] = o1 * sc;
        }
        return;
    }
    if (bid < 1024) {
        // element layout [b][h][l][dk]: j = (i>>5)&2047, h = (i>>16)&15
        int n4 = B_ * H_ * L_ * DK_ / 4;
        int i = bid * 256 + threadIdx.x;
        int stride = 1024 * 256;
        for (; i < n4; i += stride) {
            int j = (i >> 5) & (L_ - 1);
            int h = (i >> 16) & (H_ - 1);
            float l2g = log1pf(-exp2f((float)(-5 - h))) * 1.44269504088896f;
            float s = exp2f(l2g * -(float)(j & 63));   // gamma^-(j mod 64)
            float4 f = ((const float4*)kin)[i];
            uint2 o;
            o.x = (unsigned)f2bf(f.x * s) | ((unsigned)f2bf(f.y * s) << 16);
            o.y = (unsigned)f2bf(f.z * s) | ((unsigned)f2bf(f.w * s) << 16);
            ((uint2*)kb)[i] = o;
        }
        return;
    }
    int blk = bid - 1024;
    int ltile = blk & (L_/64 - 1);
    int bh = blk / (L_/64);
    const float* vp = v + ((size_t)bh * L_ + (size_t)ltile * 64) * DV_;
    unsigned short* vo = vt + (size_t)bh * DV_ * L_ + ltile * 64;
    int t = threadIdx.x;
    int r0 = t >> 5, c0 = (t & 31) * 4;
    #pragma unroll
    for (int it = 0; it < 8; ++it) {
        int row = r0 + 8 * it;
        float4 f = *(const float4*)(vp + row * DV_ + c0);
        lds[row][c0 + 0] = f2bf(f.x);
        lds[row][c0 + 1] = f2bf(f.y);
        lds[row][c0 + 2] = f2bf(f.z);
        lds[row][c0 + 3] = f2bf(f.w);
    }
    __syncthreads();
    int dvb = t >> 3, seg = t & 7;
    #pragma unroll
    for (int ot = 0; ot < 4; ++ot) {
        int dv = dvb + 32 * ot;
        unsigned short a[8];
        #pragma unroll
        for (int tt = 0; tt < 8; ++tt) {
            int pp = seg * 8 + tt;
            int js = (pp & ~12) | ((pp & 4) << 1) | ((pp & 8) >> 1);  // swap b2,b3
            a[tt] = lds[js][dv];
        }
        uint4 st;
        st.x = (unsigned)a[0] | ((unsigned)a[1] << 16);
        st.y = (unsigned)a[2] | ((unsigned)a[3] << 16);
        st.z = (unsigned)a[4] | ((unsigned)a[5] << 16);
        st.w = (unsigned)a[6] | ((unsigned)a[7] << 16);
        *(uint4*)(vo + (size_t)dv * L_ + seg * 8) = st;
    }
}

// One pipeline round at static buffer offset CUR (0 / 16384), staging the
// next tile into NXT. Protocol = proven r10: vmcnt(8) counted wait (never
// drains the fresh stage), 2 s_barrier. Decay is ONE mul (colfac folded
// into kb by prep); rowsum rides the matrix pipe via mfma(P, ones).
#define ROUND(CUR, NXT)                                                       \
{                                                                             \
    if (jt < itile) {                                                         \
        const char* ksrc = (const char*)(kbp + (size_t)(jt + 1) * KVBLK * DK_);\
        const char* vsrc = (const char*)(vtp + (jt + 1) * KVBLK);             \
        _Pragma("unroll")                                                     \
        for (int is = 0; is < 4; ++is) {                                      \
            gload_lds16(ksrc + koff[is], kLDSw + (NXT) + dwv[is]);            \
            gload_lds16(vsrc + voff[is], vLDSw + (NXT) + dwv[is]);            \
        }                                                                     \
        asm volatile("s_waitcnt vmcnt(8)" ::: "memory");                      \
    } else {                                                                  \
        asm volatile("s_waitcnt vmcnt(0)" ::: "memory");                      \
    }                                                                         \
    asm volatile("s_barrier" ::: "memory");                                   \
    f32x16 s;                                                                 \
    _Pragma("unroll")                                                         \
    for (int e = 0; e < 16; ++e) s[e] = 0.0f;                                 \
    __builtin_amdgcn_s_setprio(1);                                            \
    _Pragma("unroll")                                                         \
    for (int ks = 0; ks < 8; ++ks)                                            \
        s = __builtin_amdgcn_mfma_f32_32x32x16_bf16(                          \
                *(const bf16x8*)(ka[ks] + (CUR)), qf[ks], s, 0, 0, 0);        \
    __builtin_amdgcn_s_setprio(0);                                            \
    float ab = arow;                                                          \
    arow *= gm64i;                                                            \
    float val[16];                                                            \
    if (jt == itile) {                                                        \
        _Pragma("unroll")                                                     \
        for (int r = 0; r < 16; ++r) {                                        \
            float vv = s[r] * ab;                                             \
            val[r] = ((mbits >> r) & 1) ? vv : 0.0f;                          \
        }                                                                     \
    } else {                                                                  \
        _Pragma("unroll")                                                     \
        for (int r = 0; r < 16; ++r) val[r] = s[r] * ab;                      \
    }                                                                         \
    union { bf16x8 v; __bf16 e[8]; } P0, P1;                                  \
    _Pragma("unroll")                                                         \
    for (int e = 0; e < 8; ++e) { P0.e[e] = (__bf16)val[e];                   \
                                  P1.e[e] = (__bf16)val[8 + e]; }             \
    __builtin_amdgcn_s_setprio(1);                                            \
    _Pragma("unroll")                                                         \
    for (int nt = 0; nt < 4; ++nt) {                                          \
        o[nt] = __builtin_amdgcn_mfma_f32_32x32x16_bf16(                      \
                    P0.v, *(const bf16x8*)(va0[nt] + (CUR)), o[nt], 0, 0, 0); \
        o[nt] = __builtin_amdgcn_mfma_f32_32x32x16_bf16(                      \
                    P1.v, *(const bf16x8*)(va1[nt] + (CUR)), o[nt], 0, 0, 0); \
    }                                                                         \
    o4 = __builtin_amdgcn_mfma_f32_32x32x16_bf16(P0.v, onesv, o4, 0, 0, 0);   \
    o4 = __builtin_amdgcn_mfma_f32_32x32x16_bf16(P1.v, onesv, o4, 0, 0, 0);   \
    __builtin_amdgcn_s_setprio(0);                                            \
    asm volatile("s_barrier" ::: "memory");                                   \
}

// ---- main kernel: r10 geometry (best known, 79.8us) -- 4 waves (rh,kh),
// QBLK=64, KVBLK=64, K/V dbuf, balanced q-tile pairs {sp,31-sp}, grid 512
// = 2/CU, 2 waves/SIMD. r14's VALU diet (colfac folded into kb, rowsum
// via ones-MFMA, static dbuf offsets, setprio). REVERT of r16's dual-
// segment shared-KV: its oA+oB+qfA+qfB+temps (~280 regs) spilled to
// scratch (662MB fetch / 633MB write per dispatch) -> 4x regression.
__launch_bounds__(256, 2)
__global__ void retention_kernel(const float* __restrict__ q,
                                 const unsigned short* __restrict__ kb,
                                 const unsigned short* __restrict__ vt_,
                                 float* __restrict__ out) {
    __shared__ __align__(16) unsigned short kbuf[2][64 * 128];   // 32 KB
    __shared__ __align__(16) unsigned short vbuf[2][128 * 64];   // 32 KB
    __shared__ float rsx[32];

    // bh->XCD-pinned remap (xcd = bid%8): 4 bh per XCD -> ~4MB K+V ~= L2
    int bid = blockIdx.x;            // 0..511
    int x   = bid & 7;               // XCD id
    int t_  = bid >> 3;              // 0..63
    int hi  = t_ >> 4;               // 0..3
    int sp  = t_ & 15;               // 0..15: q-tile pair (sp, 31-sp)
    int bh = hi * 8 + x;
    int b = bh >> 4, h = bh & 15;

    int tid = threadIdx.x;
    int lane = tid & 63;
    int w = tid >> 6;                   // 0..3
    int rh = w >> 1;                    // q-row half
    int kh = w & 1;                     // kv half
    int il = lane & 31;
    int hl = lane >> 5;

    const unsigned short* kbp = kb  + (size_t)bh * L_ * DK_;
    const unsigned short* vtp = vt_ + (size_t)bh * DV_ * L_;

    // hoisted per-lane stage offsets (loop-invariant)
    int dwv[4], koff[4], voff[4];
    #pragma unroll
    for (int is = 0; is < 4; ++is) {
        int dw = is * 4096 + w * 1024;
        int d  = dw + lane * 16;
        dwv[is]  = dw;
        koff[is] = KSWZ(d);
        int sv   = VSWZ(d);
        voff[is] = (sv >> 7) * (L_ * 2) + (sv & 127);
    }
    char* kLDSw = (char*)&kbuf[0][0];
    char* vLDSw = (char*)&vbuf[0][0];

    float ex = exp2f((float)(-5 - h));
    float log2g = log1pf(-ex) * 1.44269504088896f;
    float gm64i = exp2f(log2g * (-64.0f));

    // diag mask (segment-invariant): keep iff j_local <= i_local
    int icmp = rh * 32 + il - kh * 32;
    unsigned mbits = 0;
    #pragma unroll
    for (int r = 0; r < 16; ++r)
        if (((r & 3) + 8 * (r >> 2) + 4 * hl) <= icmp) mbits |= 1u << r;

    int rswz = (il & 7) << 4;           // read-side XOR (rows == il mod 8)
    int hl16 = hl * 16;

    // hoisted LDS read addresses (buffer picked via +0/+16384 literal)
    const char* ka[8];
    #pragma unroll
    for (int ks = 0; ks < 8; ++ks)
        ka[ks] = (const char*)&kbuf[0][0] + (kh * 32 + il) * 256
                 + ((ks * 32 + hl16) ^ rswz);
    const char* va0[4];
    const char* va1[4];
    #pragma unroll
    for (int nt = 0; nt < 4; ++nt) {
        va0[nt] = (const char*)&vbuf[0][0] + (nt * 32 + il) * 128
                  + ((kh * 64 + hl16) ^ rswz);
        va1[nt] = (const char*)&vbuf[0][0] + (nt * 32 + il) * 128
                  + ((kh * 64 + 32 + hl16) ^ rswz);
    }

    union { bf16x8 v; __bf16 e[8]; } ones_;
    #pragma unroll
    for (int e = 0; e < 8; ++e) ones_.e[e] = (__bf16)1.0f;
    bf16x8 onesv = ones_.v;

    for (int seg = 0; seg < 2; ++seg) {
        int itile = seg ? (31 - sp) : sp;
        int i_base = itile * QBLK + rh * 32;
        int i_row  = i_base + il;       // this lane's q-row

        // ---- Q fragments FIRST (their waits must not drain our stages) ----
        bf16x8 qf[8];
        {
            const float* qp = q + ((size_t)bh * L_ + i_row) * DK_ + hl * 8;
            #pragma unroll
            for (int ks = 0; ks < 8; ++ks) {
                float4 f0 = *(const float4*)(qp + ks * 16);
                float4 f1 = *(const float4*)(qp + ks * 16 + 4);
                union { bf16x8 v; unsigned short u[8]; } A;
                A.u[0]=f2bf(f0.x); A.u[1]=f2bf(f0.y); A.u[2]=f2bf(f0.z); A.u[3]=f2bf(f0.w);
                A.u[4]=f2bf(f1.x); A.u[5]=f2bf(f1.y); A.u[6]=f2bf(f1.z); A.u[7]=f2bf(f1.w);
                qf[ks] = A.v;
            }
        }

        // ---- stage tile 0 into buffer offset 0 ----
        {
            const char* ksrc = (const char*)kbp;
            const char* vsrc = (const char*)vtp;
            #pragma unroll
            for (int is = 0; is < 4; ++is) {
                gload_lds16(ksrc + koff[is], kLDSw + dwv[is]);
                gload_lds16(vsrc + voff[is], vLDSw + dwv[is]);
            }
        }

        // row decay: ab = gamma^(i - jt*64); K' already carries gamma^-(j&63)
        float arow = exp2f(log2g * (float)i_row);

        f32x16 o[4];                    // O^T: lane = dv (il), regs = i-pattern
        #pragma unroll
        for (int nt = 0; nt < 4; ++nt)
            #pragma unroll
            for (int e = 0; e < 16; ++e) o[nt][e] = 0.0f;
        f32x16 o4;                      // rowsums via mfma(P, ones)
        #pragma unroll
        for (int e = 0; e < 16; ++e) o4[e] = 0.0f;

        int jt = 0;
        while (true) {                  // static buffer alternation
            ROUND(0, 16384);
            if (++jt > itile) break;
            ROUND(16384, 0);
            if (++jt > itile) break;
        }

        // ---- cross-kh reduction via LDS (tile buffers dead now) ----
        __syncthreads();   // all tile reads done before buffer reuse
        float* eb = (float*)&kbuf[0][0] + rh * 4096;   // 16KB per rh
        if (kh == 1) {
            #pragma unroll
            for (int nt = 0; nt < 4; ++nt)
                #pragma unroll
                for (int qq = 0; qq < 4; ++qq) {
                    float4 vv = { o[nt][4*qq+0], o[nt][4*qq+1],
                                  o[nt][4*qq+2], o[nt][4*qq+3] };
                    *(float4*)(eb + (nt * 4 + qq) * 256 + lane * 4) = vv;
                }
            if (lane == 0) {
                #pragma unroll
                for (int r = 0; r < 16; ++r) rsx[rh * 16 + r] = o4[r];
            }
        }
        __syncthreads();
        if (kh == 0) {
            #pragma unroll
            for (int nt = 0; nt < 4; ++nt)
                #pragma unroll
                for (int qq = 0; qq < 4; ++qq) {
                    float4 pv = *(const float4*)(eb + (nt * 4 + qq) * 256 + lane * 4);
                    o[nt][4*qq+0] += pv.x; o[nt][4*qq+1] += pv.y;
                    o[nt][4*qq+2] += pv.z; o[nt][4*qq+3] += pv.w;
                }
            #pragma unroll
            for (int r = 0; r < 16; ++r) {
                float rtot = o4[r] + rsx[rh * 16 + r];
                float dn = 1.0f / fmaxf(1.0f, fabsf(rtot));
                float ov[4]; float ss = 0.0f;
                #pragma unroll
                for (int nt = 0; nt < 4; ++nt) { ov[nt] = o[nt][r] * dn; ss += ov[nt]*ov[nt]; }
                ss += __shfl_xor(ss, 1);  ss += __shfl_xor(ss, 2);
                ss += __shfl_xor(ss, 4);  ss += __shfl_xor(ss, 8);
                ss += __shfl_xor(ss, 16);
                float sc = rsqrtf(ss * (1.0f / 128.0f) + 1e-6f);
                int isrc = (r & 3) + 8 * (r >> 2) + 4 * hl;
                int i_abs = i_base + isrc;
                if (i_abs != 0) {               // row 0 handled in prep (fp32)
                    float* op = out + (((size_t)b * L_ + i_abs) * H_ + h) * DV_ + il;
                    #pragma unroll
                    for (int nt = 0; nt < 4; ++nt) op[nt * 32] = ov[nt] * sc;
                }
            }
        }
        __syncthreads();   // exch reads done before next segment's staging
    }
}

extern "C" void kernel_launch(void* const* d_in, const int* in_sizes, int n_in,
                              void* d_out, int out_size, void* d_ws, size_t ws_size,
                              hipStream_t stream) {
    const float* q = (const float*)d_in[0];
    const float* k = (const float*)d_in[1];
    const float* v = (const float*)d_in[2];
    // d_in[3] decay_mask (256MB) and d_in[4] intra_decay are recomputed on the fly
    float* out = (float*)d_out;

    unsigned short* kb = (unsigned short*)d_ws;                 // 16 MB
    unsigned short* vt = kb + (size_t)B_ * H_ * L_ * DK_;       // 16 MB

    prep_kernel<<<2080, 256, 0, stream>>>(k, kb, v, vt, q, out);
    retention_kernel<<<512, 256, 0, stream>>>(q, kb, vt, out);
}

// Round 18
// 79.177 us; speedup vs baseline: 4.0126x; 1.0073x over previous
//
#include <hip/hip_runtime.h>
#include <hip/hip_bf16.h>
#include <math.h>

// SelfRetentionV1: B=2,H=16,L=2048,DK=128,DV=128
// out[b,l,h,d] = RMSNorm_d( (QK^T * gamma^(i-j) / max(1,|rowsum|)) @ V )
#define B_ 2
#define H_ 16
#define L_ 2048
#define DK_ 128
#define DV_ 128
#define QBLK 64
#define KVBLK 64

typedef __bf16 bf16x8 __attribute__((ext_vector_type(8)));
typedef float  f32x16 __attribute__((ext_vector_type(16)));

static __device__ __forceinline__ unsigned short f2bf(float f) {
    union { float f; unsigned int u; } x; x.f = f;
    unsigned int r = x.u + 0x7fffu + ((x.u >> 16) & 1u);  // RNE
    return (unsigned short)(r >> 16);
}

// async global->LDS, 16B per lane; LDS dest = wave-uniform base + lane*16
static __device__ __forceinline__ void gload_lds16(const void* g, void* l) {
    __builtin_amdgcn_global_load_lds(
        (const __attribute__((address_space(1))) unsigned int*)g,
        (__attribute__((address_space(3))) unsigned int*)l,
        16, 0, 0);
}

// K tile rows are 256B: swizzle bits 4-6 by row&7 (involution, row bits >=8)
#define KSWZ(d) ((d) ^ ((((d) >> 8) & 7) << 4))
// V tile rows are 128B: row bits >=7
#define VSWZ(d) ((d) ^ ((((d) >> 7) & 7) << 4))

// ---- fused pre-pass: blocks 0..1023 convert K fp32->bf16 SCALED BY
// gamma_h^-(j&63); 1024..2047 transpose V -> VT[bh][dv][perm(l)]
// (bit2<->3 perm); 2048..2079 fp32 row-0 fixup ----
__global__ void prep_kernel(const float* __restrict__ kin,
                            unsigned short* __restrict__ kb,
                            const float* __restrict__ v,
                            unsigned short* __restrict__ vt,
                            const float* __restrict__ q,
                            float* __restrict__ out) {
    __shared__ unsigned short lds[64][130];   // +2 pad (transpose half only)
    int bid = blockIdx.x;
    if (bid >= 2048) {                 // row-0 fixup, 32 blocks, wave 0 only
        if (threadIdx.x < 64) {
            int bh = bid - 2048;
            int lane = threadIdx.x;
            const float* qp = q   + (size_t)bh * L_ * DK_;
            const float* kp = kin + (size_t)bh * L_ * DK_;
            const float* vp = v   + (size_t)bh * L_ * DV_;
            float part = qp[lane] * kp[lane] + qp[lane + 64] * kp[lane + 64];
            #pragma unroll
            for (int mm = 1; mm < 64; mm <<= 1) part += __shfl_xor(part, mm);
            float cf = part / fmaxf(1.0f, fabsf(part));
            float o0 = cf * vp[lane], o1 = cf * vp[lane + 64];
            float ss = o0 * o0 + o1 * o1;
            #pragma unroll
            for (int mm = 1; mm < 64; mm <<= 1) ss += __shfl_xor(ss, mm);
            float sc = rsqrtf(ss * (1.0f / 128.0f) + 1e-6f);
            int b = bh >> 4, h = bh & 15;
            float* op = out + ((size_t)b * L_ * H_ + h) * DV_;   // i = 0
            op[lane] = o0 * sc;
            op[lane + 64] = o1 * sc;
        }
        return;
    }
    if (bid < 1024) {
        // element layout [b][h][l][dk]: j = (i>>5)&2047, h = (i>>16)&15
        int n4 = B_ * H_ * L_ * DK_ / 4;
        int i = bid * 256 + threadIdx.x;
        int stride = 1024 * 256;
        for (; i < n4; i += stride) {
            int j = (i >> 5) & (L_ - 1);
            int h = (i >> 16) & (H_ - 1);
            float l2g = log1pf(-exp2f((float)(-5 - h))) * 1.44269504088896f;
            float s = exp2f(l2g * -(float)(j & 63));   // gamma^-(j mod 64)
            float4 f = ((const float4*)kin)[i];
            uint2 o;
            o.x = (unsigned)f2bf(f.x * s) | ((unsigned)f2bf(f.y * s) << 16);
            o.y = (unsigned)f2bf(f.z * s) | ((unsigned)f2bf(f.w * s) << 16);
            ((uint2*)kb)[i] = o;
        }
        return;
    }
    int blk = bid - 1024;
    int ltile = blk & (L_/64 - 1);
    int bh = blk / (L_/64);
    const float* vp = v + ((size_t)bh * L_ + (size_t)ltile * 64) * DV_;
    unsigned short* vo = vt + (size_t)bh * DV_ * L_ + ltile * 64;
    int t = threadIdx.x;
    int r0 = t >> 5, c0 = (t & 31) * 4;
    #pragma unroll
    for (int it = 0; it < 8; ++it) {
        int row = r0 + 8 * it;
        float4 f = *(const float4*)(vp + row * DV_ + c0);
        lds[row][c0 + 0] = f2bf(f.x);
        lds[row][c0 + 1] = f2bf(f.y);
        lds[row][c0 + 2] = f2bf(f.z);
        lds[row][c0 + 3] = f2bf(f.w);
    }
    __syncthreads();
    int dvb = t >> 3, seg = t & 7;
    #pragma unroll
    for (int ot = 0; ot < 4; ++ot) {
        int dv = dvb + 32 * ot;
        unsigned short a[8];
        #pragma unroll
        for (int tt = 0; tt < 8; ++tt) {
            int pp = seg * 8 + tt;
            int js = (pp & ~12) | ((pp & 4) << 1) | ((pp & 8) >> 1);  // swap b2,b3
            a[tt] = lds[js][dv];
        }
        uint4 st;
        st.x = (unsigned)a[0] | ((unsigned)a[1] << 16);
        st.y = (unsigned)a[2] | ((unsigned)a[3] << 16);
        st.z = (unsigned)a[4] | ((unsigned)a[5] << 16);
        st.w = (unsigned)a[6] | ((unsigned)a[7] << 16);
        *(uint4*)(vo + (size_t)dv * L_ + seg * 8) = st;
    }
}

// raw barrier: LDS-only ordering (lgkm), does NOT drain vmcnt -> the
// prefetched DMA for the next segment stays in flight across the epilogue.
// Safe for the exchange: every tile ds_read is consumed by an MFMA whose
// compiler-inserted lgkm wait retires it before that wave's final s_barrier.
#define RAWBAR() asm volatile("s_waitcnt lgkmcnt(0)\n\ts_barrier" ::: "memory")

#define LOADQ(IROW)                                                          \
{                                                                            \
    const float* qp_ = q + ((size_t)bh * L_ + (IROW)) * DK_ + hl * 8;        \
    _Pragma("unroll")                                                        \
    for (int ks = 0; ks < 8; ++ks) {                                         \
        float4 f0 = *(const float4*)(qp_ + ks * 16);                         \
        float4 f1 = *(const float4*)(qp_ + ks * 16 + 4);                     \
        union { bf16x8 v; unsigned short u[8]; } A_;                         \
        A_.u[0]=f2bf(f0.x); A_.u[1]=f2bf(f0.y); A_.u[2]=f2bf(f0.z); A_.u[3]=f2bf(f0.w); \
        A_.u[4]=f2bf(f1.x); A_.u[5]=f2bf(f1.y); A_.u[6]=f2bf(f1.z); A_.u[7]=f2bf(f1.w); \
        qf[ks] = A_.v;                                                       \
    }                                                                        \
}

#define STAGE0(OFF)                                                          \
{                                                                            \
    const char* ksrc_ = (const char*)kbp;                                    \
    const char* vsrc_ = (const char*)vtp;                                    \
    _Pragma("unroll")                                                        \
    for (int is = 0; is < 4; ++is) {                                         \
        gload_lds16(ksrc_ + koff[is], kLDSw + (OFF) + dwv[is]);              \
        gload_lds16(vsrc_ + voff[is], vLDSw + (OFF) + dwv[is]);              \
    }                                                                        \
}

#define RESETO()                                                             \
{                                                                            \
    _Pragma("unroll")                                                        \
    for (int nt = 0; nt < 4; ++nt)                                           \
        _Pragma("unroll")                                                    \
        for (int e = 0; e < 16; ++e) o[nt][e] = 0.0f;                        \
    _Pragma("unroll")                                                        \
    for (int e = 0; e < 16; ++e) o4[e] = 0.0f;                               \
}

// One pipeline round at static buffer offset CUR (0 / 16384), staging the
// next tile into NXT. Protocol = proven r10/r14: vmcnt(8) counted wait
// (never drains the fresh stage), 2 s_barrier. Decay is ONE mul (colfac
// folded into kb by prep); rowsum rides the matrix pipe via mfma(P, ones).
#define ROUND(CUR, NXT)                                                       \
{                                                                             \
    if (jt < itile) {                                                         \
        const char* ksrc = (const char*)(kbp + (size_t)(jt + 1) * KVBLK * DK_);\
        const char* vsrc = (const char*)(vtp + (jt + 1) * KVBLK);             \
        _Pragma("unroll")                                                     \
        for (int is = 0; is < 4; ++is) {                                      \
            gload_lds16(ksrc + koff[is], kLDSw + (NXT) + dwv[is]);            \
            gload_lds16(vsrc + voff[is], vLDSw + (NXT) + dwv[is]);            \
        }                                                                     \
        asm volatile("s_waitcnt vmcnt(8)" ::: "memory");                      \
    } else {                                                                  \
        asm volatile("s_waitcnt vmcnt(0)" ::: "memory");                      \
    }                                                                         \
    asm volatile("s_barrier" ::: "memory");                                   \
    f32x16 s;                                                                 \
    _Pragma("unroll")                                                         \
    for (int e = 0; e < 16; ++e) s[e] = 0.0f;                                 \
    __builtin_amdgcn_s_setprio(1);                                            \
    _Pragma("unroll")                                                         \
    for (int ks = 0; ks < 8; ++ks)                                            \
        s = __builtin_amdgcn_mfma_f32_32x32x16_bf16(                          \
                *(const bf16x8*)(ka[ks] + (CUR)), qf[ks], s, 0, 0, 0);        \
    __builtin_amdgcn_s_setprio(0);                                            \
    float ab = arow;                                                          \
    arow *= gm64i;                                                            \
    float val[16];                                                            \
    if (jt == itile) {                                                        \
        _Pragma("unroll")                                                     \
        for (int r = 0; r < 16; ++r) {                                        \
            float vv = s[r] * ab;                                             \
            val[r] = ((mbits >> r) & 1) ? vv : 0.0f;                          \
        }                                                                     \
    } else {                                                                  \
        _Pragma("unroll")                                                     \
        for (int r = 0; r < 16; ++r) val[r] = s[r] * ab;                      \
    }                                                                         \
    union { bf16x8 v; __bf16 e[8]; } P0, P1;                                  \
    _Pragma("unroll")                                                         \
    for (int e = 0; e < 8; ++e) { P0.e[e] = (__bf16)val[e];                   \
                                  P1.e[e] = (__bf16)val[8 + e]; }             \
    __builtin_amdgcn_s_setprio(1);                                            \
    _Pragma("unroll")                                                         \
    for (int nt = 0; nt < 4; ++nt) {                                          \
        o[nt] = __builtin_amdgcn_mfma_f32_32x32x16_bf16(                      \
                    P0.v, *(const bf16x8*)(va0[nt] + (CUR)), o[nt], 0, 0, 0); \
        o[nt] = __builtin_amdgcn_mfma_f32_32x32x16_bf16(                      \
                    P1.v, *(const bf16x8*)(va1[nt] + (CUR)), o[nt], 0, 0, 0); \
    }                                                                         \
    o4 = __builtin_amdgcn_mfma_f32_32x32x16_bf16(P0.v, onesv, o4, 0, 0, 0);   \
    o4 = __builtin_amdgcn_mfma_f32_32x32x16_bf16(P1.v, onesv, o4, 0, 0, 0);   \
    __builtin_amdgcn_s_setprio(0);                                            \
    asm volatile("s_barrier" ::: "memory");                                   \
}

// Epilogue: cross-kh reduce via LDS exchange at byte offset EXOFF (the
// buffer half NOT being prefetched into), then normalize + RMSNorm + store.
// rh0 exchanges in kbuf+EXOFF, rh1 in vbuf+EXOFF (16KB each).
#define EPILOGUE(IBASE, EXOFF)                                                \
{                                                                             \
    RAWBAR();                                                                 \
    float* eb = (float*)((rh ? vLDSw : kLDSw) + (EXOFF));                     \
    if (kh == 1) {                                                            \
        _Pragma("unroll")                                                     \
        for (int nt = 0; nt < 4; ++nt)                                        \
            _Pragma("unroll")                                                 \
            for (int qq = 0; qq < 4; ++qq) {                                  \
                float4 vv = { o[nt][4*qq+0], o[nt][4*qq+1],                   \
                              o[nt][4*qq+2], o[nt][4*qq+3] };                 \
                *(float4*)(eb + (nt * 4 + qq) * 256 + lane * 4) = vv;         \
            }                                                                 \
        if (lane == 0) {                                                      \
            _Pragma("unroll")                                                 \
            for (int r = 0; r < 16; ++r) rsx[rh * 16 + r] = o4[r];            \
        }                                                                     \
    }                                                                         \
    RAWBAR();                                                                 \
    if (kh == 0) {                                                            \
        _Pragma("unroll")                                                     \
        for (int nt = 0; nt < 4; ++nt)                                        \
            _Pragma("unroll")                                                 \
            for (int qq = 0; qq < 4; ++qq) {                                  \
                float4 pv = *(const float4*)(eb + (nt * 4 + qq) * 256 + lane * 4); \
                o[nt][4*qq+0] += pv.x; o[nt][4*qq+1] += pv.y;                 \
                o[nt][4*qq+2] += pv.z; o[nt][4*qq+3] += pv.w;                 \
            }                                                                 \
        _Pragma("unroll")                                                     \
        for (int r = 0; r < 16; ++r) {                                        \
            float rtot = o4[r] + rsx[rh * 16 + r];                            \
            float dn = 1.0f / fmaxf(1.0f, fabsf(rtot));                       \
            float ov[4]; float ss = 0.0f;                                     \
            _Pragma("unroll")                                                 \
            for (int nt = 0; nt < 4; ++nt) { ov[nt] = o[nt][r] * dn; ss += ov[nt]*ov[nt]; } \
            ss += __shfl_xor(ss, 1);  ss += __shfl_xor(ss, 2);                \
            ss += __shfl_xor(ss, 4);  ss += __shfl_xor(ss, 8);                \
            ss += __shfl_xor(ss, 16);                                         \
            float sc = rsqrtf(ss * (1.0f / 128.0f) + 1e-6f);                  \
            int isrc = (r & 3) + 8 * (r >> 2) + 4 * hl;                       \
            int i_abs = (IBASE) + isrc;                                       \
            if (i_abs != 0) {               /* row 0 handled in prep (fp32) */\
                float* op = out + (((size_t)b * L_ + i_abs) * H_ + h) * DV_ + il; \
                _Pragma("unroll")                                             \
                for (int nt = 0; nt < 4; ++nt) op[nt * 32] = ov[nt] * sc;     \
            }                                                                 \
        }                                                                     \
    }                                                                         \
    RAWBAR();   /* exchange reads done before this memory is restaged */      \
}

// ---- main kernel: r10 geometry (best known, 79.75us) -- 4 waves (rh,kh),
// QBLK=64, KVBLK=64, K/V dbuf, balanced q-tile pairs {sp,31-sp}, grid 512
// = 2/CU, 2 waves/SIMD, r14 VALU diet. NEW this round: segment-boundary
// overlap -- seg-B Q load + tile-0 DMA issued BEFORE epilogue A, and
// epilogue barriers are raw lgkm-only (no vmcnt drain), so the prefetch
// hides under the ~1500cy epilogue instead of serializing after it.
__launch_bounds__(256, 2)
__global__ void retention_kernel(const float* __restrict__ q,
                                 const unsigned short* __restrict__ kb,
                                 const unsigned short* __restrict__ vt_,
                                 float* __restrict__ out) {
    __shared__ __align__(16) unsigned short kbuf[2][64 * 128];   // 32 KB
    __shared__ __align__(16) unsigned short vbuf[2][128 * 64];   // 32 KB
    __shared__ float rsx[32];

    // bh->XCD-pinned remap (xcd = bid%8): 4 bh per XCD -> ~4MB K+V ~= L2
    int bid = blockIdx.x;            // 0..511
    int x   = bid & 7;               // XCD id
    int t_  = bid >> 3;              // 0..63
    int hi  = t_ >> 4;               // 0..3
    int sp  = t_ & 15;               // 0..15: q-tile pair (sp, 31-sp)
    int bh = hi * 8 + x;
    int b = bh >> 4, h = bh & 15;

    int tid = threadIdx.x;
    int lane = tid & 63;
    int w = tid >> 6;                   // 0..3
    int rh = w >> 1;                    // q-row half
    int kh = w & 1;                     // kv half
    int il = lane & 31;
    int hl = lane >> 5;

    const unsigned short* kbp = kb  + (size_t)bh * L_ * DK_;
    const unsigned short* vtp = vt_ + (size_t)bh * DV_ * L_;

    // hoisted per-lane stage offsets (loop-invariant)
    int dwv[4], koff[4], voff[4];
    #pragma unroll
    for (int is = 0; is < 4; ++is) {
        int dw = is * 4096 + w * 1024;
        int d  = dw + lane * 16;
        dwv[is]  = dw;
        koff[is] = KSWZ(d);
        int sv   = VSWZ(d);
        voff[is] = (sv >> 7) * (L_ * 2) + (sv & 127);
    }
    char* kLDSw = (char*)&kbuf[0][0];
    char* vLDSw = (char*)&vbuf[0][0];

    float ex = exp2f((float)(-5 - h));
    float log2g = log1pf(-ex) * 1.44269504088896f;
    float gm64i = exp2f(log2g * (-64.0f));

    // diag mask (segment-invariant): keep iff j_local <= i_local
    int icmp = rh * 32 + il - kh * 32;
    unsigned mbits = 0;
    #pragma unroll
    for (int r = 0; r < 16; ++r)
        if (((r & 3) + 8 * (r >> 2) + 4 * hl) <= icmp) mbits |= 1u << r;

    int rswz = (il & 7) << 4;           // read-side XOR (rows == il mod 8)
    int hl16 = hl * 16;

    // hoisted LDS read addresses (buffer picked via +0/+16384 literal)
    const char* ka[8];
    #pragma unroll
    for (int ks = 0; ks < 8; ++ks)
        ka[ks] = (const char*)&kbuf[0][0] + (kh * 32 + il) * 256
                 + ((ks * 32 + hl16) ^ rswz);
    const char* va0[4];
    const char* va1[4];
    #pragma unroll
    for (int nt = 0; nt < 4; ++nt) {
        va0[nt] = (const char*)&vbuf[0][0] + (nt * 32 + il) * 128
                  + ((kh * 64 + hl16) ^ rswz);
        va1[nt] = (const char*)&vbuf[0][0] + (nt * 32 + il) * 128
                  + ((kh * 64 + 32 + hl16) ^ rswz);
    }

    union { bf16x8 v; __bf16 e[8]; } ones_;
    #pragma unroll
    for (int e = 0; e < 8; ++e) ones_.e[e] = (__bf16)1.0f;
    bf16x8 onesv = ones_.v;

    int itileA = sp;                 // 0..15
    int itileB = 31 - sp;            // 16..31
    int i0A = itileA * QBLK + rh * 32;
    int i0B = itileB * QBLK + rh * 32;

    bf16x8 qf[8];
    f32x16 o[4], o4;
    float arow;

    // ================= segment A =================
    LOADQ(i0A + il);                 // Q first: its waits drain nothing of ours
    STAGE0(0);
    arow = exp2f(log2g * (float)(i0A + il));
    RESETO();
    {
        int itile = itileA;
        int jt = 0;
        while (true) {
            ROUND(0, 16384);
            if (++jt > itile) break;
            ROUND(16384, 0);
            if (++jt > itile) break;
        }
    }

    // ---- boundary: prefetch seg B under epilogue A ----
    // last round drained vmcnt(0): zero outstanding -> LOADQ's implicit
    // waits are free; then tile-0-B DMA targets the free buffer half.
    LOADQ(i0B + il);
    int startB = ((itileA + 1) & 1) * 16384;   // free buffer half
    int exA    = (itileA & 1) * 16384;         // last-read half -> exchange
    STAGE0(startB);

    EPILOGUE(i0A, exA);

    // ================= segment B =================
    arow = exp2f(log2g * (float)(i0B + il));
    RESETO();
    {
        int itile = itileB;
        int jt = 0;
        if (startB == 0) {
            while (true) {
                ROUND(0, 16384);
                if (++jt > itile) break;
                ROUND(16384, 0);
                if (++jt > itile) break;
            }
        } else {
            while (true) {
                ROUND(16384, 0);
                if (++jt > itile) break;
                ROUND(0, 16384);
                if (++jt > itile) break;
            }
        }
    }
    EPILOGUE(i0B, 0);
}

extern "C" void kernel_launch(void* const* d_in, const int* in_sizes, int n_in,
                              void* d_out, int out_size, void* d_ws, size_t ws_size,
                              hipStream_t stream) {
    const float* q = (const float*)d_in[0];
    const float* k = (const float*)d_in[1];
    const float* v = (const float*)d_in[2];
    // d_in[3] decay_mask (256MB) and d_in[4] intra_decay are recomputed on the fly
    float* out = (float*)d_out;

    unsigned short* kb = (unsigned short*)d_ws;                 // 16 MB
    unsigned short* vt = kb + (size_t)B_ * H_ * L_ * DK_;       // 16 MB

    prep_kernel<<<2080, 256, 0, stream>>>(k, kb, v, vt, q, out);
    retention_kernel<<<512, 256, 0, stream>>>(q, kb, vt, out);
}